// Round 2
// baseline (1495.458 us; speedup 1.0000x reference)
//
#include <hip/hip_runtime.h>

typedef __bf16 bf16x8 __attribute__((ext_vector_type(8)));
typedef float f32x4 __attribute__((ext_vector_type(4)));

#define T_LEN 200
#define NB 4096
#define NTILE 256            // NB/16 row-tiles

// workspace layout: [0, 16384): per-tile progress counters, 64B stride (memset to 0 each launch)
//                   [32768, 32768 + 256*200*16*4): scores, f32 [tile][t][16]
#define WS_CNT_STRIDE 16     // u32s (64 B)
#define WS_SCORE_OFF  32768

__device__ __forceinline__ f32x4 mfma16(bf16x8 a, bf16x8 b, f32x4 c) {
    return __builtin_amdgcn_mfma_f32_16x16x32_bf16(a, b, c, 0, 0, 0);
}
__device__ __forceinline__ float sigf(float x) {
    return __builtin_amdgcn_rcpf(1.0f + __expf(-x));
}
__device__ __forceinline__ float tanh_fast(float x) {
    return 1.0f - 2.0f * __builtin_amdgcn_rcpf(__expf(2.0f * x) + 1.0f);
}
__device__ __forceinline__ unsigned packRNE2(float a, float b) {
    unsigned ha = (unsigned)__builtin_bit_cast(unsigned short, (__bf16)a);
    unsigned hb = (unsigned)__builtin_bit_cast(unsigned short, (__bf16)b);
    return ha | (hb << 16);
}
__device__ __forceinline__ void publish_hi(unsigned short* hp, float v) {
    __bf16 h = (__bf16)v;
    *hp = __builtin_bit_cast(unsigned short, h);
}

struct Frag { bf16x8 hi, lo; };
__device__ __forceinline__ Frag make_frag(f32x4 a, f32x4 b) {
    Frag f;
    #pragma unroll
    for (int j = 0; j < 4; j++) {
        float v = a[j]; __bf16 h = (__bf16)v;
        f.hi[j] = h; f.lo[j] = (__bf16)(v - (float)h);
    }
    #pragma unroll
    for (int j = 0; j < 4; j++) {
        float v = b[j]; __bf16 h = (__bf16)v;
        f.hi[4 + j] = h; f.lo[4 + j] = (__bf16)(v - (float)h);
    }
    return f;
}
__device__ __forceinline__ bf16x8 load_w(const float* p) {
    f32x4 a = *(const f32x4*)p, b = *(const f32x4*)(p + 4);
    bf16x8 w;
    #pragma unroll
    for (int j = 0; j < 4; j++) { w[j] = (__bf16)a[j]; w[4 + j] = (__bf16)b[j]; }
    return w;
}

// ================== Split-block schedule ==================
// grid 512 x 256 threads. Block b < 256: GRU role (tile b). Block b >= 256: AUGRU role (tile b-256).
// Each role is its own 4-wave barrier domain; 2 blocks co-resident per CU overlap stalls.
//
// G (1 __syncthreads per step): section t:
//   read x(t) frags from sX[t&1]          (staged section t-1)
//   read h(t-1) frags fr from sHG[(t-1)&1] (published section t-1)
//   score(t-1) = fr . tp  -> sigmoid -> global wsScore (wave0 diag lanes)
//   12 MFMAs, gates, h(t) -> publish sHG[t&1]
//   pack x(t+1) -> sX[(t+1)&1]; issue load x(t+2)
//   release counter (=t, scores 0..t-1 ready) every 4 steps (tid 0, agent scope)
//   __syncthreads()
// Buffers double-buffered; every RAW/WAR crosses >=1 barrier (checked per-buffer).
//
// A (2 __syncthreads per step, lags G by >=1 step; self-gathers x):
//   phase0(t): [every 4 steps: acquire-spin counter >= min(t+4,200)]
//     issue score(t) loads (consumed at phase0(t+1))
//     read x(t) frags; if t>0: read rh frags, 2 MFMA, tanh, apply score(t-1) (reg),
//     update ha(t-1), publish sHA; x-preact MFMAs (6); stage x(t+1); load x(t+2)
//   b_mid
//   phase1(t): read ha frags, 4 MFMA, sigmoids, publish rh; scoreV = scoreN
//   b_end
__global__ __launch_bounds__(256, 2)
void dien_split(const int* __restrict__ u_idx, const int* __restrict__ i_idx,
                const int* __restrict__ seq, const float* __restrict__ item_emb,
                const float* __restrict__ user_bias, const float* __restrict__ item_bias,
                const float* __restrict__ gw_ih, const float* __restrict__ gb_ih,
                const float* __restrict__ gw_hh, const float* __restrict__ gb_hh,
                const float* __restrict__ attn_w, const float* __restrict__ attn_b,
                const float* __restrict__ wr_w, const float* __restrict__ wr_b,
                const float* __restrict__ wz_w, const float* __restrict__ wz_b,
                const float* __restrict__ wh_w, const float* __restrict__ wh_b,
                const float* __restrict__ aux_w, const float* __restrict__ aux_b,
                float* __restrict__ out, unsigned* __restrict__ wsCnt,
                float* __restrict__ wsScore)
{
    __shared__ int sSeq[16][T_LEN];
    __shared__ __align__(16) unsigned short sX[2][16][72];
    // G-only
    __shared__ __align__(16) float sTP[16][64];
    __shared__ __align__(16) unsigned short sHG[2][16][72];
    __shared__ float sParts[16][4];
    // A-only
    __shared__ __align__(16) unsigned short sHA[16][72];
    __shared__ __align__(16) unsigned short sRH[16][72];

    const int tid  = threadIdx.x;        // 0..255
    const int wg   = tid >> 6;           // wave 0..3
    const int lane = tid & 63;
    const int c    = lane & 15;
    const int q    = lane >> 4;
    const bool isGB = (blockIdx.x < NTILE);
    const int tile  = isGB ? blockIdx.x : (blockIdx.x - NTILE);
    const int row0  = tile * 16;
    const int dglob = wg * 16 + c;
    const int xrow  = wg * 4 + q;        // staging row for this lane
    const int xch   = c;                 // 4-float chunk within row

    // ---- stage seq indices (both roles) ----
    for (int i = tid; i < 16 * T_LEN; i += 256) {
        int b = i / T_LEN, t = i - b * T_LEN;
        sSeq[b][t] = seq[(row0 + b) * T_LEN + t];
    }
    // ---- prime sX[0] with x(0) (both roles) ----
    {
        const float* p = item_emb + (long)seq[(row0 + xrow) * T_LEN + 0] * 64 + xch * 4;
        f32x4 v = *(const f32x4*)p;
        *(uint2*)&sX[0][xrow][xch * 4] =
            make_uint2(packRNE2(v[0], v[1]), packRNE2(v[2], v[3]));
    }

    if (isGB) {
        // ---- fm1 ----
        if (tid < 16) {
            int b = row0 + tid;
            out[b] = user_bias[u_idx[b]] + item_bias[i_idx[b]];
        }
        // ---- target_proj 16x64 fp32 ----
        {
            int b  = tid >> 4;
            int d0 = (tid & 15) * 4;
            const float* erow = item_emb + (long)i_idx[row0 + b] * 64;
            float e[64];
            #pragma unroll
            for (int k4 = 0; k4 < 16; k4++) {
                f32x4 v = *(const f32x4*)(erow + k4 * 4);
                #pragma unroll
                for (int j = 0; j < 4; j++) e[k4 * 4 + j] = v[j];
            }
            #pragma unroll
            for (int dd = 0; dd < 4; dd++) {
                int d = d0 + dd;
                const float* wrow = attn_w + d * 64;
                float s = attn_b[d];
                #pragma unroll
                for (int k4 = 0; k4 < 16; k4++) {
                    f32x4 wv = *(const f32x4*)(wrow + k4 * 4);
                    #pragma unroll
                    for (int j = 0; j < 4; j++) s += e[k4 * 4 + j] * wv[j];
                }
                sTP[b][d] = s;
            }
        }
        // zero sHG[1] (h(-1) = 0 read at section 0)
        for (int i = tid; i < 16 * 72; i += 256) ((unsigned short*)sHG[1])[i] = 0;
        __syncthreads();

        // ---- weights (bf16-hi RNE) ----
        bf16x8 W[12];
        #pragma unroll
        for (int g = 0; g < 3; g++)
            #pragma unroll
            for (int s = 0; s < 2; s++) {
                W[g * 2 + s]     = load_w(gw_ih + (g * 64 + dglob) * 64 + s * 32 + q * 8);
                W[6 + g * 2 + s] = load_w(gw_hh + (g * 64 + dglob) * 64 + s * 32 + q * 8);
            }
        const float bA = gb_ih[dglob] + gb_hh[dglob];
        const float bB = gb_ih[64 + dglob] + gb_hh[64 + dglob];
        const float bC = gb_ih[128 + dglob];
        const float bD = gb_hh[128 + dglob];
        const float auxwc = aux_w[dglob];

        Frag tpB0 = make_frag(*(const f32x4*)&sTP[c][q * 8], *(const f32x4*)&sTP[c][q * 8 + 4]);
        Frag tpB1 = make_frag(*(const f32x4*)&sTP[c][32 + q * 8], *(const f32x4*)&sTP[c][32 + q * 8 + 4]);

        float hst[4] = {0.f, 0.f, 0.f, 0.f};
        f32x4 xnxt = *(const f32x4*)(item_emb + (long)sSeq[xrow][1] * 64 + xch * 4);
        unsigned* cnt = wsCnt + (size_t)tile * WS_CNT_STRIDE;
        float* scoreBase = wsScore + (long)tile * T_LEN * 16;

        for (int t = 0; t < T_LEN; t++) {
            // x(t) frags (staged section t-1)
            bf16x8 x0 = *(const bf16x8*)&sX[t & 1][c][q * 8];
            bf16x8 x1 = *(const bf16x8*)&sX[t & 1][c][32 + q * 8];
            // h(t-1) frags (published section t-1)
            bf16x8 fr0 = *(const bf16x8*)&sHG[(t + 1) & 1][c][q * 8];
            bf16x8 fr1 = *(const bf16x8*)&sHG[(t + 1) & 1][c][32 + q * 8];

            // score(t-1) = diag(h(t-1) . tp^T), publish to workspace
            if (t > 0) {
                f32x4 sc = {0.f, 0.f, 0.f, 0.f};
                sc = mfma16(fr0, tpB0.hi, sc); sc = mfma16(fr0, tpB0.lo, sc);
                sc = mfma16(fr1, tpB1.hi, sc); sc = mfma16(fr1, tpB1.lo, sc);
                if (wg == 0 && (c >> 2) == q) {
                    int i = c & 3;
                    float d = (i == 0) ? sc[0] : (i == 1) ? sc[1] : (i == 2) ? sc[2] : sc[3];
                    __hip_atomic_store(scoreBase + (long)(t - 1) * 16 + c, sigf(d),
                                       __ATOMIC_RELAXED, __HIP_MEMORY_SCOPE_AGENT);
                }
            }

            // GRU step
            int tn = t + 2; if (tn > T_LEN - 1) tn = T_LEN - 1;
            f32x4 xg = *(const f32x4*)(item_emb + (long)sSeq[xrow][tn] * 64 + xch * 4);

            f32x4 accR = {bA, bA, bA, bA};
            accR = mfma16(x0, W[0], accR); accR = mfma16(x1, W[1], accR);
            accR = mfma16(fr0, W[6], accR); accR = mfma16(fr1, W[7], accR);
            f32x4 accZ = {bB, bB, bB, bB};
            accZ = mfma16(x0, W[2], accZ); accZ = mfma16(x1, W[3], accZ);
            accZ = mfma16(fr0, W[8], accZ); accZ = mfma16(fr1, W[9], accZ);
            f32x4 accNX = {bC, bC, bC, bC};
            accNX = mfma16(x0, W[4], accNX); accNX = mfma16(x1, W[5], accNX);
            f32x4 accNH = {bD, bD, bD, bD};
            accNH = mfma16(fr0, W[10], accNH); accNH = mfma16(fr1, W[11], accNH);

            #pragma unroll
            for (int i = 0; i < 4; i++) {
                float r = sigf(accR[i]);
                float z = sigf(accZ[i]);
                float n = tanh_fast(accNX[i] + r * accNH[i]);
                float hn = n + z * (hst[i] - n);
                hst[i] = hn;
                publish_hi(&sHG[t & 1][q * 4 + i][dglob], hn);
            }

            // stage x(t+1); advance gather pipeline
            *(uint2*)&sX[(t + 1) & 1][xrow][xch * 4] =
                make_uint2(packRNE2(xnxt[0], xnxt[1]), packRNE2(xnxt[2], xnxt[3]));
            xnxt = xg;

            // progress release every 4 steps (scores 0..t-1 are stored)
            if (tid == 0 && (t & 3) == 3)
                __hip_atomic_store(cnt, (unsigned)t, __ATOMIC_RELEASE, __HIP_MEMORY_SCOPE_AGENT);

            __syncthreads();
        }

        // ---- epilogue: score(199) ----
        {
            bf16x8 f0 = *(const bf16x8*)&sHG[(T_LEN - 1) & 1][c][q * 8];
            bf16x8 f1 = *(const bf16x8*)&sHG[(T_LEN - 1) & 1][c][32 + q * 8];
            f32x4 sc = {0.f, 0.f, 0.f, 0.f};
            sc = mfma16(f0, tpB0.hi, sc); sc = mfma16(f0, tpB0.lo, sc);
            sc = mfma16(f1, tpB1.hi, sc); sc = mfma16(f1, tpB1.lo, sc);
            if (wg == 0 && (c >> 2) == q) {
                int i = c & 3;
                float d = (i == 0) ? sc[0] : (i == 1) ? sc[1] : (i == 2) ? sc[2] : sc[3];
                __hip_atomic_store(scoreBase + (long)(T_LEN - 1) * 16 + c, sigf(d),
                                   __ATOMIC_RELAXED, __HIP_MEMORY_SCOPE_AGENT);
            }
        }
        if (tid == 0)
            __hip_atomic_store(cnt, (unsigned)T_LEN, __ATOMIC_RELEASE, __HIP_MEMORY_SCOPE_AGENT);

        // ---- aux_logits ----
        {
            float pa[4];
            #pragma unroll
            for (int i = 0; i < 4; i++) pa[i] = hst[i] * auxwc;
            #pragma unroll
            for (int m = 1; m < 16; m <<= 1) {
                #pragma unroll
                for (int i = 0; i < 4; i++) pa[i] += __shfl_xor(pa[i], m, 64);
            }
            if (c == 0) {
                #pragma unroll
                for (int i = 0; i < 4; i++) sParts[q * 4 + i][wg] = pa[i];
            }
        }
        __syncthreads();
        if (tid < 16) {
            out[NB + NB * 64 + row0 + tid] =
                sParts[tid][0] + sParts[tid][1] + sParts[tid][2] + sParts[tid][3] + aux_b[0];
        }
    } else {
        // ================= AUGRU block =================
        for (int i = tid; i < 16 * 72; i += 256) ((unsigned short*)sHA)[i] = 0;
        __syncthreads();

        bf16x8 W[12];
        #pragma unroll
        for (int s = 0; s < 2; s++) {
            const int fo = dglob * 128 + s * 32 + q * 8;
            W[0 + s]  = load_w(wr_w + fo);
            W[2 + s]  = load_w(wr_w + fo + 64);
            W[4 + s]  = load_w(wz_w + fo);
            W[6 + s]  = load_w(wz_w + fo + 64);
            W[8 + s]  = load_w(wh_w + fo);
            W[10 + s] = load_w(wh_w + fo + 64);
        }
        const float bA = wr_b[dglob];
        const float bB = wz_b[dglob];
        const float bC = wh_b[dglob];

        float hst[4] = {0.f, 0.f, 0.f, 0.f};
        f32x4 aAH = {0.f, 0.f, 0.f, 0.f};
        float z_c[4] = {0.f, 0.f, 0.f, 0.f};
        f32x4 scoreV = {0.f, 0.f, 0.f, 0.f};
        f32x4 scoreN = {0.f, 0.f, 0.f, 0.f};
        f32x4 xnxt = *(const f32x4*)(item_emb + (long)sSeq[xrow][1] * 64 + xch * 4);
        const unsigned* cnt = wsCnt + (size_t)tile * WS_CNT_STRIDE;
        const float* scoreBase = wsScore + (long)tile * T_LEN * 16;

        for (int t = 0; t < T_LEN; t++) {
            f32x4 aAR, aAZ;

            // ---- phase 0 ----
            if ((t & 3) == 0) {
                unsigned need = (unsigned)((t + 4 < T_LEN) ? (t + 4) : T_LEN);
                while (__hip_atomic_load(cnt, __ATOMIC_ACQUIRE, __HIP_MEMORY_SCOPE_AGENT) < need)
                    __builtin_amdgcn_s_sleep(8);
            }
            // prefetch score(t) (guaranteed published; consumed at phase0(t+1))
            {
                const float* sp = scoreBase + (long)t * 16 + q * 4;
                #pragma unroll
                for (int i = 0; i < 4; i++)
                    scoreN[i] = __hip_atomic_load(sp + i, __ATOMIC_RELAXED, __HIP_MEMORY_SCOPE_AGENT);
            }

            bf16x8 x0 = *(const bf16x8*)&sX[t & 1][c][q * 8];
            bf16x8 x1 = *(const bf16x8*)&sX[t & 1][c][32 + q * 8];

            if (t > 0) {
                bf16x8 rh0 = *(const bf16x8*)&sRH[c][q * 8];
                bf16x8 rh1 = *(const bf16x8*)&sRH[c][32 + q * 8];
                aAH = mfma16(rh0, W[10], aAH); aAH = mfma16(rh1, W[11], aAH);
                #pragma unroll
                for (int i = 0; i < 4; i++) {
                    int rr = q * 4 + i;
                    float a = scoreV[i];              // score(t-1), rows q*4+i
                    float hh = tanh_fast(aAH[i]);
                    float zz = a * z_c[i];
                    float hv = hst[i] + zz * (hh - hst[i]);
                    hst[i] = hv;
                    publish_hi(&sHA[rr][dglob], hv);
                }
            }
            aAR = (f32x4){bA, bA, bA, bA};
            aAR = mfma16(x0, W[0], aAR); aAR = mfma16(x1, W[1], aAR);
            aAZ = (f32x4){bB, bB, bB, bB};
            aAZ = mfma16(x0, W[4], aAZ); aAZ = mfma16(x1, W[5], aAZ);
            aAH = (f32x4){bC, bC, bC, bC};
            aAH = mfma16(x0, W[8], aAH); aAH = mfma16(x1, W[9], aAH);

            // stage x(t+1); advance gather pipeline
            int tn = t + 2; if (tn > T_LEN - 1) tn = T_LEN - 1;
            f32x4 xg = *(const f32x4*)(item_emb + (long)sSeq[xrow][tn] * 64 + xch * 4);
            *(uint2*)&sX[(t + 1) & 1][xrow][xch * 4] =
                make_uint2(packRNE2(xnxt[0], xnxt[1]), packRNE2(xnxt[2], xnxt[3]));
            xnxt = xg;

            __syncthreads();  // b_mid

            // ---- phase 1 ----
            bf16x8 ha0 = *(const bf16x8*)&sHA[c][q * 8];
            bf16x8 ha1 = *(const bf16x8*)&sHA[c][32 + q * 8];
            aAR = mfma16(ha0, W[2], aAR); aAR = mfma16(ha1, W[3], aAR);
            aAZ = mfma16(ha0, W[6], aAZ); aAZ = mfma16(ha1, W[7], aAZ);
            #pragma unroll
            for (int i = 0; i < 4; i++) {
                float r = sigf(aAR[i]);
                z_c[i]  = sigf(aAZ[i]);
                float rh = r * hst[i];
                publish_hi(&sRH[q * 4 + i][dglob], rh);
            }
            scoreV = scoreN;

            __syncthreads();  // b_end
        }

        // ---- epilogue: finalize ha(T-1), write attn_vec ----
        {
            bf16x8 rh0 = *(const bf16x8*)&sRH[c][q * 8];
            bf16x8 rh1 = *(const bf16x8*)&sRH[c][32 + q * 8];
            aAH = mfma16(rh0, W[10], aAH); aAH = mfma16(rh1, W[11], aAH);
            #pragma unroll
            for (int i = 0; i < 4; i++) {
                int rr = q * 4 + i;
                float a = scoreV[i];                  // score(199)
                float hh = tanh_fast(aAH[i]);
                float zz = a * z_c[i];
                float hv = hst[i] + zz * (hh - hst[i]);
                out[NB + (row0 + rr) * 64 + dglob] = hv;
            }
        }
    }
}

extern "C" void kernel_launch(void* const* d_in, const int* in_sizes, int n_in,
                              void* d_out, int out_size, void* d_ws, size_t ws_size,
                              hipStream_t stream) {
    // zero per-tile progress counters each launch (graph-capture safe stream op)
    hipMemsetAsync(d_ws, 0, 16384, stream);
    dien_split<<<dim3(512), dim3(256), 0, stream>>>(
        (const int*)d_in[0],      // u_idx
        (const int*)d_in[1],      // i_idx
        (const int*)d_in[2],      // seq
        (const float*)d_in[3],    // item_emb
        (const float*)d_in[4],    // user_bias
        (const float*)d_in[5],    // item_bias
        (const float*)d_in[6],    // gru_w_ih
        (const float*)d_in[7],    // gru_b_ih
        (const float*)d_in[8],    // gru_w_hh
        (const float*)d_in[9],    // gru_b_hh
        (const float*)d_in[10],   // attn_w
        (const float*)d_in[11],   // attn_b
        (const float*)d_in[12],   // wr_w
        (const float*)d_in[13],   // wr_b
        (const float*)d_in[14],   // wz_w
        (const float*)d_in[15],   // wz_b
        (const float*)d_in[16],   // wh_w
        (const float*)d_in[17],   // wh_b
        (const float*)d_in[18],   // aux_w
        (const float*)d_in[19],   // aux_b
        (float*)d_out,
        (unsigned*)d_ws,
        (float*)((char*)d_ws + WS_SCORE_OFF));
}

// Round 3
// 331.861 us; speedup vs baseline: 4.5063x; 4.5063x over previous
//
#include <hip/hip_runtime.h>

typedef __bf16 bf16x8 __attribute__((ext_vector_type(8)));
typedef float f32x4 __attribute__((ext_vector_type(4)));

#define T_LEN 200
#define NB 4096

__device__ __forceinline__ f32x4 mfma16(bf16x8 a, bf16x8 b, f32x4 c) {
    return __builtin_amdgcn_mfma_f32_16x16x32_bf16(a, b, c, 0, 0, 0);
}
// raw v_rcp_f32 (1 ulp) transcendentals; saturation exact (rcp(inf)=0)
__device__ __forceinline__ float sigf(float x) {
    return __builtin_amdgcn_rcpf(1.0f + __expf(-x));
}
__device__ __forceinline__ float tanh_fast(float x) {
    return 1.0f - 2.0f * __builtin_amdgcn_rcpf(__expf(2.0f * x) + 1.0f);
}
__device__ __forceinline__ unsigned packRNE2(float a, float b) {
    unsigned ha = (unsigned)__builtin_bit_cast(unsigned short, (__bf16)a);
    unsigned hb = (unsigned)__builtin_bit_cast(unsigned short, (__bf16)b);
    return ha | (hb << 16);
}
__device__ __forceinline__ void publish_hi(unsigned short* hp, float v) {
    __bf16 h = (__bf16)v;
    *hp = __builtin_bit_cast(unsigned short, h);
}
__device__ __forceinline__ bf16x8 load_w(const float* p) {   // W: bf16 RNE hi only
    f32x4 a = *(const f32x4*)p, b = *(const f32x4*)(p + 4);
    bf16x8 w;
    #pragma unroll
    for (int j = 0; j < 4; j++) { w[j] = (__bf16)a[j]; w[4 + j] = (__bf16)b[j]; }
    return w;
}

// Single-block schedule (r13 lineage), restructured for short per-phase chains:
// 8 waves: 0-3 GRU (G), 4-7 AUGRU (A). AUGRU pipelined one step behind.
// Changes vs 186us baseline:
//  - sHG, sX double-buffered: G's transposed-frag read of h(t-1) moved to
//    phase0(t) (crosses b_end), removing the S1 LDS round-trip.
//  - score path: no MFMA / no LDS re-read. G computes per-wave partials from
//    f32 hst registers (4 fma + 4 shfl_xor), writes sPart[t&1][row][wg].
//    A sums 4 partials + sigmoid at phase0(t+1). (More accurate than old
//    bf16-frag score MFMA; removes tp frags and wg0 divergence.)
//  - G phase split: phase0 = frag reads + 12 MFMA (no trans); phase1 = gates +
//    publish + score-shuffle + x staging. A unchanged except score source.
// Hazards (every producer->consumer crosses >=1 barrier; b_mid/b_end per step):
//  sX[2]  : W G phase1(t) buf (t+1)&1; R G+A phase0(t+1). WAR: prev R at
//           phase0(t-1), >=2 barriers before W.
//  sHG[2] : W G phase1(t) buf t&1; R G phase0(t+1). WAR: prev R phase0(t-1)
//           (buf t&1), >=3 barriers before W.
//  sPart[2]: W G phase1(t) buf t&1; R A phase0(t+1). WAR analogous.
//  sHA    : W A phase0(t), R A phase1(t) [b_mid]. WAR: R phase1(t-1) [b_end].
//  sRH    : W A phase1(t), R A phase0(t+1)/epilogue [b_end]. WAR: R phase0(t) [b_mid].
__global__ __launch_bounds__(512, 2)
void dien_fused(const int* __restrict__ u_idx, const int* __restrict__ i_idx,
                const int* __restrict__ seq, const float* __restrict__ item_emb,
                const float* __restrict__ user_bias, const float* __restrict__ item_bias,
                const float* __restrict__ gw_ih, const float* __restrict__ gb_ih,
                const float* __restrict__ gw_hh, const float* __restrict__ gb_hh,
                const float* __restrict__ attn_w, const float* __restrict__ attn_b,
                const float* __restrict__ wr_w, const float* __restrict__ wr_b,
                const float* __restrict__ wz_w, const float* __restrict__ wz_b,
                const float* __restrict__ wh_w, const float* __restrict__ wh_b,
                const float* __restrict__ aux_w, const float* __restrict__ aux_b,
                float* __restrict__ out)
{
    __shared__ int sSeq[16][T_LEN];
    __shared__ __align__(16) float sTP[16][64];
    __shared__ __align__(16) unsigned short sHG[2][16][72];
    __shared__ __align__(16) unsigned short sHA[16][72];
    __shared__ __align__(16) unsigned short sRH[16][72];
    __shared__ __align__(16) unsigned short sX[2][16][72];
    __shared__ __align__(16) float sPart[2][16][4];
    __shared__ float sParts[16][4];

    const int tid  = threadIdx.x;
    const int wave = tid >> 6;           // 0..7
    const int lane = tid & 63;
    const int c    = lane & 15;
    const int q    = lane >> 4;
    const bool isG = (wave < 4);
    const int wg   = wave & 3;
    const int dglob = wg * 16 + c;
    const int row0 = blockIdx.x * 16;

    // ---- stage seq indices ----
    for (int i = tid; i < 16 * T_LEN; i += 512) {
        int b = i / T_LEN, t = i - b * T_LEN;
        sSeq[b][t] = seq[(row0 + b) * T_LEN + t];
    }

    // ---- fm1 ----
    if (tid < 16) {
        int b = row0 + tid;
        out[b] = user_bias[u_idx[b]] + item_bias[i_idx[b]];
    }

    // ---- target_proj (16x64 fp32), threads 0..255 ----
    if (tid < 256) {
        int b  = tid >> 4;
        int d0 = (tid & 15) * 4;
        const float* erow = item_emb + (long)i_idx[row0 + b] * 64;
        float e[64];
        #pragma unroll
        for (int k4 = 0; k4 < 16; k4++) {
            f32x4 v = *(const f32x4*)(erow + k4 * 4);
            #pragma unroll
            for (int j = 0; j < 4; j++) e[k4 * 4 + j] = v[j];
        }
        #pragma unroll
        for (int dd = 0; dd < 4; dd++) {
            int d = d0 + dd;
            const float* wrow = attn_w + d * 64;
            float s = attn_b[d];
            #pragma unroll
            for (int k4 = 0; k4 < 16; k4++) {
                f32x4 wv = *(const f32x4*)(wrow + k4 * 4);
                #pragma unroll
                for (int j = 0; j < 4; j++) s += e[k4 * 4 + j] * wv[j];
            }
            sTP[b][d] = s;
        }
    }

    // ---- zero sHA (A phase1(0) reads) and sHG[1] (G phase0(0) reads) ----
    for (int i = tid; i < 16 * 72; i += 512) {
        ((unsigned short*)sHA)[i]    = 0;
        ((unsigned short*)sHG[1])[i] = 0;
    }
    // ---- prime sX[0] with x(0) (G lanes: 16 rows x 16 chunks) ----
    const int xrow = wg * 4 + q;         // producer row (G)
    const int xch  = c;                  // 4-float chunk within row
    if (isG) {
        const float* p = item_emb + (long)seq[(row0 + xrow) * T_LEN + 0] * 64 + xch * 4;
        f32x4 v = *(const f32x4*)p;
        *(uint2*)&sX[0][xrow][xch * 4] =
            make_uint2(packRNE2(v[0], v[1]), packRNE2(v[2], v[3]));
    }
    __syncthreads();

    // ---- register-resident weights (bf16-hi RNE), unioned across groups ----
    // G: W[0..1]=wih_r, W[2..3]=wih_z, W[4..5]=wih_n, W[6..7]=whh_r, W[8..9]=whh_z, W[10..11]=whh_n
    // A: W[0..1]=wrx, W[2..3]=wrh, W[4..5]=wzx, W[6..7]=wzh, W[8..9]=whx, W[10..11]=whhat
    bf16x8 W[12];
    if (isG) {
        #pragma unroll
        for (int g = 0; g < 3; g++)
            #pragma unroll
            for (int s = 0; s < 2; s++) {
                W[g * 2 + s]     = load_w(gw_ih + (g * 64 + dglob) * 64 + s * 32 + q * 8);
                W[6 + g * 2 + s] = load_w(gw_hh + (g * 64 + dglob) * 64 + s * 32 + q * 8);
            }
    } else {
        #pragma unroll
        for (int s = 0; s < 2; s++) {
            const int fo = dglob * 128 + s * 32 + q * 8;
            W[0 + s]  = load_w(wr_w + fo);
            W[2 + s]  = load_w(wr_w + fo + 64);
            W[4 + s]  = load_w(wz_w + fo);
            W[6 + s]  = load_w(wz_w + fo + 64);
            W[8 + s]  = load_w(wh_w + fo);
            W[10 + s] = load_w(wh_w + fo + 64);
        }
    }

    float bA, bB, bC, bD;
    if (isG) {
        bA = gb_ih[dglob] + gb_hh[dglob];
        bB = gb_ih[64 + dglob] + gb_hh[64 + dglob];
        bC = gb_ih[128 + dglob];
        bD = gb_hh[128 + dglob];
    } else {
        bA = wr_b[dglob];
        bB = wz_b[dglob];
        bC = wh_b[dglob];
        bD = 0.0f;
    }
    const float auxwc = aux_w[dglob];

    // per-lane target-proj scalars for the in-register score dot:
    // lane (c,q) holds rows q*4+i, dim dglob
    float tpT[4];
    if (isG) {
        #pragma unroll
        for (int i = 0; i < 4; i++) tpT[i] = sTP[q * 4 + i][dglob];
    }

    // ---- state ----
    float hst[4] = {0.f, 0.f, 0.f, 0.f};   // G: hg(t); A: ha(t-1)
    f32x4 aAH = {0.f, 0.f, 0.f, 0.f};
    float z_c[4] = {0.f, 0.f, 0.f, 0.f};

    // ---- x prefetch pipeline prologue (G): xnxt = x(1) ----
    f32x4 xnxt = {0.f, 0.f, 0.f, 0.f};
    if (isG) xnxt = *(const f32x4*)(item_emb + (long)sSeq[xrow][1] * 64 + xch * 4);

    f32x4 accR, accZ, accNX, accNH;          // G: live phase0 -> phase1
    f32x4 aAR, aAZ;                          // A: live phase0 -> phase1
    f32x4 xg;                                // G: x(t+2) raw, becomes xnxt

    for (int t = 0; t < T_LEN; t++) {
        // ================= phase 0 =================
        if (isG) {
            // reads: x(t) frags, h(t-1) frags (buf (t-1)&1 == (t+1)&1)
            bf16x8 x0  = *(const bf16x8*)&sX[t & 1][c][q * 8];
            bf16x8 x1  = *(const bf16x8*)&sX[t & 1][c][32 + q * 8];
            bf16x8 fr0 = *(const bf16x8*)&sHG[(t + 1) & 1][c][q * 8];
            bf16x8 fr1 = *(const bf16x8*)&sHG[(t + 1) & 1][c][32 + q * 8];

            int tn = t + 2; if (tn > T_LEN - 1) tn = T_LEN - 1;
            xg = *(const f32x4*)(item_emb + (long)sSeq[xrow][tn] * 64 + xch * 4);

            accR = (f32x4){bA, bA, bA, bA};
            accR = mfma16(x0, W[0], accR); accR = mfma16(x1, W[1], accR);
            accR = mfma16(fr0, W[6], accR); accR = mfma16(fr1, W[7], accR);
            accZ = (f32x4){bB, bB, bB, bB};
            accZ = mfma16(x0, W[2], accZ); accZ = mfma16(x1, W[3], accZ);
            accZ = mfma16(fr0, W[8], accZ); accZ = mfma16(fr1, W[9], accZ);
            accNX = (f32x4){bC, bC, bC, bC};
            accNX = mfma16(x0, W[4], accNX); accNX = mfma16(x1, W[5], accNX);
            accNH = (f32x4){bD, bD, bD, bD};
            accNH = mfma16(fr0, W[10], accNH); accNH = mfma16(fr1, W[11], accNH);
        } else {
            bf16x8 x0 = *(const bf16x8*)&sX[t & 1][c][q * 8];
            bf16x8 x1 = *(const bf16x8*)&sX[t & 1][c][32 + q * 8];

            aAR = (f32x4){bA, bA, bA, bA};
            aAR = mfma16(x0, W[0], aAR); aAR = mfma16(x1, W[1], aAR);
            aAZ = (f32x4){bB, bB, bB, bB};
            aAZ = mfma16(x0, W[4], aAZ); aAZ = mfma16(x1, W[5], aAZ);

            if (t > 0) {
                bf16x8 rh0 = *(const bf16x8*)&sRH[c][q * 8];
                bf16x8 rh1 = *(const bf16x8*)&sRH[c][32 + q * 8];
                f32x4 pv0 = *(const f32x4*)&sPart[(t + 1) & 1][q * 4 + 0][0];
                f32x4 pv1 = *(const f32x4*)&sPart[(t + 1) & 1][q * 4 + 1][0];
                f32x4 pv2 = *(const f32x4*)&sPart[(t + 1) & 1][q * 4 + 2][0];
                f32x4 pv3 = *(const f32x4*)&sPart[(t + 1) & 1][q * 4 + 3][0];
                aAH = mfma16(rh0, W[10], aAH); aAH = mfma16(rh1, W[11], aAH);
                #pragma unroll
                for (int i = 0; i < 4; i++) {
                    int rr = q * 4 + i;
                    f32x4 pv = (i == 0) ? pv0 : (i == 1) ? pv1 : (i == 2) ? pv2 : pv3;
                    float a = sigf((pv[0] + pv[1]) + (pv[2] + pv[3]));   // score(t-1)
                    float hh = tanh_fast(aAH[i]);
                    float zz = a * z_c[i];
                    float hv = hst[i] + zz * (hh - hst[i]);
                    hst[i] = hv;
                    publish_hi(&sHA[rr][dglob], hv);
                }
            }
            // reseed aAH for step t (x-part of h_hat preactivation)
            aAH = (f32x4){bC, bC, bC, bC};
            aAH = mfma16(x0, W[8], aAH); aAH = mfma16(x1, W[9], aAH);
        }

        __syncthreads();  // b_mid

        // ================= phase 1 =================
        if (isG) {
            float pa[4];
            #pragma unroll
            for (int i = 0; i < 4; i++) {
                float r = sigf(accR[i]);
                float z = sigf(accZ[i]);
                float n = tanh_fast(accNX[i] + r * accNH[i]);
                float hn = n + z * (hst[i] - n);
                hst[i] = hn;
                publish_hi(&sHG[t & 1][q * 4 + i][dglob], hn);
                pa[i] = hn * tpT[i];          // score partial (f32, this wave's 16 dims)
            }
            // reduce over the 16 c-lanes (lane = q*16+c; xor bits 0..3 stay in group)
            #pragma unroll
            for (int m = 1; m < 16; m <<= 1) {
                #pragma unroll
                for (int i = 0; i < 4; i++) pa[i] += __shfl_xor(pa[i], m, 64);
            }
            if (c == 0) {
                #pragma unroll
                for (int i = 0; i < 4; i++) sPart[t & 1][q * 4 + i][wg] = pa[i];
            }
            // stage x(t+1) (RNE bf16) from the register loaded at phase0(t-1)
            *(uint2*)&sX[(t + 1) & 1][xrow][xch * 4] =
                make_uint2(packRNE2(xnxt[0], xnxt[1]), packRNE2(xnxt[2], xnxt[3]));
            xnxt = xg;
        } else {
            bf16x8 ha0 = *(const bf16x8*)&sHA[c][q * 8];
            bf16x8 ha1 = *(const bf16x8*)&sHA[c][32 + q * 8];
            aAR = mfma16(ha0, W[2], aAR); aAR = mfma16(ha1, W[3], aAR);
            aAZ = mfma16(ha0, W[6], aAZ); aAZ = mfma16(ha1, W[7], aAZ);
            #pragma unroll
            for (int i = 0; i < 4; i++) {
                float r = sigf(aAR[i]);
                z_c[i]  = sigf(aAZ[i]);
                float rh = r * hst[i];
                publish_hi(&sRH[q * 4 + i][dglob], rh);
            }
        }

        __syncthreads();  // b_end
    }

    // ---- epilogue: A finalizes ha(T-1), writes attn_vec ----
    if (!isG) {
        bf16x8 rh0 = *(const bf16x8*)&sRH[c][q * 8];
        bf16x8 rh1 = *(const bf16x8*)&sRH[c][32 + q * 8];
        aAH = mfma16(rh0, W[10], aAH); aAH = mfma16(rh1, W[11], aAH);
        #pragma unroll
        for (int i = 0; i < 4; i++) {
            int rr = q * 4 + i;
            f32x4 pv = *(const f32x4*)&sPart[(T_LEN - 1) & 1][rr][0];
            float a = sigf((pv[0] + pv[1]) + (pv[2] + pv[3]));   // score(T-1)
            float hh = tanh_fast(aAH[i]);
            float zz = a * z_c[i];
            float hv = hst[i] + zz * (hh - hst[i]);
            out[NB + (row0 + rr) * 64 + dglob] = hv;
        }
    }

    // ---- aux_logits from hg(T-1) (G group) ----
    if (isG) {
        float pa[4];
        #pragma unroll
        for (int i = 0; i < 4; i++) pa[i] = hst[i] * auxwc;
        #pragma unroll
        for (int m = 1; m < 16; m <<= 1) {
            #pragma unroll
            for (int i = 0; i < 4; i++) pa[i] += __shfl_xor(pa[i], m, 64);
        }
        if (c == 0) {
            #pragma unroll
            for (int i = 0; i < 4; i++) sParts[q * 4 + i][wg] = pa[i];
        }
    }
    __syncthreads();
    if (tid < 16) {
        out[NB + NB * 64 + row0 + tid] =
            sParts[tid][0] + sParts[tid][1] + sParts[tid][2] + sParts[tid][3] + aux_b[0];
    }
}

extern "C" void kernel_launch(void* const* d_in, const int* in_sizes, int n_in,
                              void* d_out, int out_size, void* d_ws, size_t ws_size,
                              hipStream_t stream) {
    dien_fused<<<dim3(256), dim3(512), 0, stream>>>(
        (const int*)d_in[0],      // u_idx
        (const int*)d_in[1],      // i_idx
        (const int*)d_in[2],      // seq
        (const float*)d_in[3],    // item_emb
        (const float*)d_in[4],    // user_bias
        (const float*)d_in[5],    // item_bias
        (const float*)d_in[6],    // gru_w_ih
        (const float*)d_in[7],    // gru_b_ih
        (const float*)d_in[8],    // gru_w_hh
        (const float*)d_in[9],    // gru_b_hh
        (const float*)d_in[10],   // attn_w
        (const float*)d_in[11],   // attn_b
        (const float*)d_in[12],   // wr_w
        (const float*)d_in[13],   // wr_b
        (const float*)d_in[14],   // wz_w
        (const float*)d_in[15],   // wz_b
        (const float*)d_in[16],   // wh_w
        (const float*)d_in[17],   // wh_b
        (const float*)d_in[18],   // aux_w
        (const float*)d_in[19],   // aux_b
        (float*)d_out);
}

// Round 4
// 262.544 us; speedup vs baseline: 5.6960x; 1.2640x over previous
//
#include <hip/hip_runtime.h>

typedef __bf16 bf16x8 __attribute__((ext_vector_type(8)));
typedef float f32x4 __attribute__((ext_vector_type(4)));

#define T_LEN 200
#define NB 4096

__device__ __forceinline__ f32x4 mfma16(bf16x8 a, bf16x8 b, f32x4 c) {
    return __builtin_amdgcn_mfma_f32_16x16x32_bf16(a, b, c, 0, 0, 0);
}
// raw v_rcp_f32 (1 ulp) transcendentals; saturation exact (rcp(inf)=0)
__device__ __forceinline__ float sigf(float x) {
    return __builtin_amdgcn_rcpf(1.0f + __expf(-x));
}
__device__ __forceinline__ float tanh_fast(float x) {
    return 1.0f - 2.0f * __builtin_amdgcn_rcpf(__expf(2.0f * x) + 1.0f);
}

// LDS-only barrier: orders all LDS ops (lgkmcnt) across the rendezvous but
// deliberately does NOT drain vmcnt -- in-flight global gathers (xg pipeline)
// stay outstanding across the barrier. __syncthreads() would emit
// s_waitcnt vmcnt(0) before s_barrier, putting the HBM gather latency on the
// critical path of EVERY step (this was the ~1100cy/step unexplained stall;
// it is also why deepening the prefetch in R0 changed nothing).
// Safe because all in-loop cross-wave traffic is LDS; the only in-loop global
// accesses are read-only item_emb loads into registers.
__device__ __forceinline__ void barrier_lds() {
    asm volatile("s_waitcnt lgkmcnt(0)\n\ts_barrier" ::: "memory");
}

// ---- RNE bf16 pack of two floats -> one dword ----
__device__ __forceinline__ unsigned packRNE2(float a, float b) {
    unsigned ha = (unsigned)__builtin_bit_cast(unsigned short, (__bf16)a);
    unsigned hb = (unsigned)__builtin_bit_cast(unsigned short, (__bf16)b);
    return ha | (hb << 16);
}
// ---- RNE hi-only publish (h-state exchanges) ----
__device__ __forceinline__ void publish_hi(unsigned short* hp, float v) {
    __bf16 h = (__bf16)v;
    *hp = __builtin_bit_cast(unsigned short, h);
}

struct Frag { bf16x8 hi, lo; };
__device__ __forceinline__ Frag make_frag(f32x4 a, f32x4 b) {
    Frag f;
    #pragma unroll
    for (int j = 0; j < 4; j++) {
        float v = a[j]; __bf16 h = (__bf16)v;
        f.hi[j] = h; f.lo[j] = (__bf16)(v - (float)h);
    }
    #pragma unroll
    for (int j = 0; j < 4; j++) {
        float v = b[j]; __bf16 h = (__bf16)v;
        f.hi[4 + j] = h; f.lo[4 + j] = (__bf16)(v - (float)h);
    }
    return f;
}
__device__ __forceinline__ bf16x8 load_w(const float* p) {   // W: bf16 RNE hi only
    f32x4 a = *(const f32x4*)p, b = *(const f32x4*)(p + 4);
    bf16x8 w;
    #pragma unroll
    for (int j = 0; j < 4; j++) { w[j] = (__bf16)a[j]; w[4 + j] = (__bf16)b[j]; }
    return w;
}

// Schedule = R13 structure (186us measured), x prefetched two steps deep.
// ONLY change this round: in-loop barriers are lgkmcnt-only (barrier_lds).
// 8 waves: 0-3 GRU (G), 4-7 AUGRU (A). AUGRU pipelined one step.
// LDS hazards (producer -> consumer crosses >=1 barrier):
//   sX  : W by G in S1(t) [x(t+1)], R by G+A in S0(t+1)   [b_end]
//   sHG : W by G in S0(t), R by G in S1(t)                 [b_mid]
//   sScore[p]: W by G(wg0) in S1(t) (p=t&1, pre-sigmoided), R by A in S0(t+1) [b_end]
//   sHA : W by A in S0(t), R by A in S1(t)                 [b_mid]
//   sRH : W by A in S1(t), R by A in S0(t+1)/epilogue      [b_end]
__global__ __launch_bounds__(512, 2)
void dien_fused(const int* __restrict__ u_idx, const int* __restrict__ i_idx,
                const int* __restrict__ seq, const float* __restrict__ item_emb,
                const float* __restrict__ user_bias, const float* __restrict__ item_bias,
                const float* __restrict__ gw_ih, const float* __restrict__ gb_ih,
                const float* __restrict__ gw_hh, const float* __restrict__ gb_hh,
                const float* __restrict__ attn_w, const float* __restrict__ attn_b,
                const float* __restrict__ wr_w, const float* __restrict__ wr_b,
                const float* __restrict__ wz_w, const float* __restrict__ wz_b,
                const float* __restrict__ wh_w, const float* __restrict__ wh_b,
                const float* __restrict__ aux_w, const float* __restrict__ aux_b,
                float* __restrict__ out)
{
    __shared__ int sSeq[16][T_LEN];
    __shared__ __align__(16) float sTP[16][64];
    __shared__ __align__(16) unsigned short sHGhi[16][72];
    __shared__ __align__(16) unsigned short sHAhi[16][72];
    __shared__ __align__(16) unsigned short sRHhi[16][72];
    __shared__ __align__(16) unsigned short sXhi[16][72];
    __shared__ float sScore[2][16];
    __shared__ float sParts[16][4];

    const int tid  = threadIdx.x;
    const int wave = tid >> 6;           // 0..7
    const int lane = tid & 63;
    const int c    = lane & 15;
    const int q    = lane >> 4;
    const bool isG = (wave < 4);
    const int wg   = wave & 3;
    const int dglob = wg * 16 + c;
    const int row0 = blockIdx.x * 16;

    // ---- stage seq indices ----
    for (int i = tid; i < 16 * T_LEN; i += 512) {
        int b = i / T_LEN, t = i - b * T_LEN;
        sSeq[b][t] = seq[(row0 + b) * T_LEN + t];
    }

    // ---- fm1 ----
    if (tid < 16) {
        int b = row0 + tid;
        out[b] = user_bias[u_idx[b]] + item_bias[i_idx[b]];
    }

    // ---- target_proj (16x64 fp32), threads 0..255 ----
    if (tid < 256) {
        int b  = tid >> 4;
        int d0 = (tid & 15) * 4;
        const float* erow = item_emb + (long)i_idx[row0 + b] * 64;
        float e[64];
        #pragma unroll
        for (int k4 = 0; k4 < 16; k4++) {
            f32x4 v = *(const f32x4*)(erow + k4 * 4);
            #pragma unroll
            for (int j = 0; j < 4; j++) e[k4 * 4 + j] = v[j];
        }
        #pragma unroll
        for (int dd = 0; dd < 4; dd++) {
            int d = d0 + dd;
            const float* wrow = attn_w + d * 64;
            float s = attn_b[d];
            #pragma unroll
            for (int k4 = 0; k4 < 16; k4++) {
                f32x4 wv = *(const f32x4*)(wrow + k4 * 4);
                #pragma unroll
                for (int j = 0; j < 4; j++) s += e[k4 * 4 + j] * wv[j];
            }
            sTP[b][d] = s;
        }
    }

    // ---- zero ha exchange buffer (A S1(0) reads it); prime sX with x(0) ----
    for (int i = tid; i < 16 * 72; i += 512) sHAhi[0][i] = 0;
    const int xrow = wg * 4 + (lane >> 4);   // producer row (G)
    const int xch  = lane & 15;              // 4-float chunk within row
    if (isG) {
        const float* p = item_emb + (long)seq[(row0 + xrow) * T_LEN + 0] * 64 + xch * 4;
        f32x4 v = *(const f32x4*)p;
        *(uint2*)&sXhi[xrow][xch * 4] =
            make_uint2(packRNE2(v[0], v[1]), packRNE2(v[2], v[3]));
    }
    __syncthreads();

    // ---- register-resident weights (bf16-hi RNE), unioned across groups ----
    // G: W[0..1]=wih_r, W[2..3]=wih_z, W[4..5]=wih_n, W[6..7]=whh_r, W[8..9]=whh_z, W[10..11]=whh_n
    // A: W[0..1]=wrx, W[2..3]=wrh, W[4..5]=wzx, W[6..7]=wzh, W[8..9]=whx, W[10..11]=whhat
    bf16x8 W[12];
    if (isG) {
        #pragma unroll
        for (int g = 0; g < 3; g++)
            #pragma unroll
            for (int s = 0; s < 2; s++) {
                W[g * 2 + s]     = load_w(gw_ih + (g * 64 + dglob) * 64 + s * 32 + q * 8);
                W[6 + g * 2 + s] = load_w(gw_hh + (g * 64 + dglob) * 64 + s * 32 + q * 8);
            }
    } else {
        #pragma unroll
        for (int s = 0; s < 2; s++) {
            const int fo = dglob * 128 + s * 32 + q * 8;
            W[0 + s]  = load_w(wr_w + fo);
            W[2 + s]  = load_w(wr_w + fo + 64);
            W[4 + s]  = load_w(wz_w + fo);
            W[6 + s]  = load_w(wz_w + fo + 64);
            W[8 + s]  = load_w(wh_w + fo);
            W[10 + s] = load_w(wh_w + fo + 64);
        }
    }

    float bA, bB, bC, bD;
    if (isG) {
        bA = gb_ih[dglob] + gb_hh[dglob];
        bB = gb_ih[64 + dglob] + gb_hh[64 + dglob];
        bC = gb_ih[128 + dglob];
        bD = gb_hh[128 + dglob];
    } else {
        bA = wr_b[dglob];
        bB = wz_b[dglob];
        bC = wh_b[dglob];
        bD = 0.0f;
    }
    const float auxwc = aux_w[dglob];

    // TP as B-fragment (G only), hi/lo (score feeds sigmoid; keep accurate)
    Frag tpB0, tpB1;
    if (isG) {
        tpB0 = make_frag(*(const f32x4*)&sTP[c][q * 8], *(const f32x4*)&sTP[c][q * 8 + 4]);
        tpB1 = make_frag(*(const f32x4*)&sTP[c][32 + q * 8], *(const f32x4*)&sTP[c][32 + q * 8 + 4]);
    }

    // ---- state ----
    float hst[4] = {0.f, 0.f, 0.f, 0.f};   // G: hg(t); A: ha(t-1)
    bf16x8 fr0, fr1;                        // G: hg(t-1) hi-frags; A: scratch
    #pragma unroll
    for (int j = 0; j < 8; j++) { fr0[j] = (__bf16)0.f; fr1[j] = (__bf16)0.f; }
    f32x4 aAH = {0.f, 0.f, 0.f, 0.f};
    float z_c[4] = {0.f, 0.f, 0.f, 0.f};

    // ---- x prefetch pipeline prologue (G): xnxt = x(1) ----
    f32x4 xnxt = {0.f, 0.f, 0.f, 0.f};
    if (isG) {
        int t1 = (T_LEN > 1) ? 1 : 0;
        xnxt = *(const f32x4*)(item_emb + (long)sSeq[xrow][t1] * 64 + xch * 4);
    }

    for (int t = 0; t < T_LEN; t++) {
        f32x4 xg;         // G: x(t+2) raw (global), becomes xnxt at end of S1
        f32x4 aAR, aAZ;   // A: r/z preactivations, live S0 -> S1

        // ================= Section 0 =================
        bf16x8 x0 = *(const bf16x8*)&sXhi[c][q * 8];
        bf16x8 x1 = *(const bf16x8*)&sXhi[c][32 + q * 8];

        if (isG) {
            int tn = t + 2; if (tn > T_LEN - 1) tn = T_LEN - 1;
            xg = *(const f32x4*)(item_emb + (long)sSeq[xrow][tn] * 64 + xch * 4);

            f32x4 accR = {bA, bA, bA, bA};
            accR = mfma16(x0, W[0], accR); accR = mfma16(x1, W[1], accR);
            accR = mfma16(fr0, W[6], accR); accR = mfma16(fr1, W[7], accR);
            f32x4 accZ = {bB, bB, bB, bB};
            accZ = mfma16(x0, W[2], accZ); accZ = mfma16(x1, W[3], accZ);
            accZ = mfma16(fr0, W[8], accZ); accZ = mfma16(fr1, W[9], accZ);
            f32x4 accNX = {bC, bC, bC, bC};
            accNX = mfma16(x0, W[4], accNX); accNX = mfma16(x1, W[5], accNX);
            f32x4 accNH = {bD, bD, bD, bD};
            accNH = mfma16(fr0, W[10], accNH); accNH = mfma16(fr1, W[11], accNH);

            #pragma unroll
            for (int i = 0; i < 4; i++) {
                float r = sigf(accR[i]);
                float z = sigf(accZ[i]);
                float n = tanh_fast(accNX[i] + r * accNH[i]);
                float hn = n + z * (hst[i] - n);
                hst[i] = hn;
                publish_hi(&sHGhi[q * 4 + i][dglob], hn);
            }
        } else {
            if (t > 0) {
                bf16x8 rh0 = *(const bf16x8*)&sRHhi[c][q * 8];
                bf16x8 rh1 = *(const bf16x8*)&sRHhi[c][32 + q * 8];
                aAH = mfma16(rh0, W[10], aAH); aAH = mfma16(rh1, W[11], aAH);
                #pragma unroll
                for (int i = 0; i < 4; i++) {
                    int rr = q * 4 + i;
                    float a = sScore[(t - 1) & 1][rr];   // pre-sigmoided
                    float hh = tanh_fast(aAH[i]);
                    float zz = a * z_c[i];
                    float hv = hst[i] + zz * (hh - hst[i]);
                    hst[i] = hv;
                    publish_hi(&sHAhi[rr][dglob], hv);
                }
            }
            aAR = (f32x4){bA, bA, bA, bA};
            aAR = mfma16(x0, W[0], aAR); aAR = mfma16(x1, W[1], aAR);
            aAZ = (f32x4){bB, bB, bB, bB};
            aAZ = mfma16(x0, W[4], aAZ); aAZ = mfma16(x1, W[5], aAZ);
            aAH = (f32x4){bC, bC, bC, bC};
            aAH = mfma16(x0, W[8], aAH); aAH = mfma16(x1, W[9], aAH);
        }

        barrier_lds();  // b_mid (LDS-only; xg stays in flight)

        // ================= Section 1 =================
        if (isG) {
            fr0 = *(const bf16x8*)&sHGhi[c][q * 8];
            fr1 = *(const bf16x8*)&sHGhi[c][32 + q * 8];
            // score(t) = diag(hg(t) . tp^T) via MFMA (hg hi x tp hi/lo)
            f32x4 sc = {0.f, 0.f, 0.f, 0.f};
            sc = mfma16(fr0, tpB0.hi, sc); sc = mfma16(fr0, tpB0.lo, sc);
            sc = mfma16(fr1, tpB1.hi, sc); sc = mfma16(fr1, tpB1.lo, sc);
            if (wg == 0 && (c >> 2) == q) {
                int i = c & 3;
                float d = (i == 0) ? sc[0] : (i == 1) ? sc[1] : (i == 2) ? sc[2] : sc[3];
                sScore[t & 1][c] = sigf(d);
            }
            // stage x(t+1) (RNE bf16) into sX from the register loaded at S0(t-1)
            *(uint2*)&sXhi[xrow][xch * 4] =
                make_uint2(packRNE2(xnxt[0], xnxt[1]), packRNE2(xnxt[2], xnxt[3]));
            xnxt = xg;
        } else {
            bf16x8 ha0 = *(const bf16x8*)&sHAhi[c][q * 8];
            bf16x8 ha1 = *(const bf16x8*)&sHAhi[c][32 + q * 8];
            aAR = mfma16(ha0, W[2], aAR); aAR = mfma16(ha1, W[3], aAR);
            aAZ = mfma16(ha0, W[6], aAZ); aAZ = mfma16(ha1, W[7], aAZ);
            #pragma unroll
            for (int i = 0; i < 4; i++) {
                float r = sigf(aAR[i]);
                z_c[i]  = sigf(aAZ[i]);
                float rh = r * hst[i];
                publish_hi(&sRHhi[q * 4 + i][dglob], rh);
            }
        }

        barrier_lds();  // b_end (LDS-only; xg stays in flight)
    }

    // ---- epilogue: A finalizes ha(T-1), writes attn_vec ----
    if (!isG) {
        bf16x8 rh0 = *(const bf16x8*)&sRHhi[c][q * 8];
        bf16x8 rh1 = *(const bf16x8*)&sRHhi[c][32 + q * 8];
        aAH = mfma16(rh0, W[10], aAH); aAH = mfma16(rh1, W[11], aAH);
        #pragma unroll
        for (int i = 0; i < 4; i++) {
            int rr = q * 4 + i;
            float a = sScore[(T_LEN - 1) & 1][rr];
            float hh = tanh_fast(aAH[i]);
            float zz = a * z_c[i];
            float hv = hst[i] + zz * (hh - hst[i]);
            out[NB + (row0 + rr) * 64 + dglob] = hv;
        }
    }

    // ---- aux_logits from hg(T-1) (G group) ----
    if (isG) {
        float pa[4];
        #pragma unroll
        for (int i = 0; i < 4; i++) pa[i] = hst[i] * auxwc;
        #pragma unroll
        for (int m = 1; m < 16; m <<= 1) {
            #pragma unroll
            for (int i = 0; i < 4; i++) pa[i] += __shfl_xor(pa[i], m, 64);
        }
        if (c == 0) {
            #pragma unroll
            for (int i = 0; i < 4; i++) sParts[q * 4 + i][wg] = pa[i];
        }
    }
    __syncthreads();
    if (tid < 16) {
        out[NB + NB * 64 + row0 + tid] =
            sParts[tid][0] + sParts[tid][1] + sParts[tid][2] + sParts[tid][3] + aux_b[0];
    }
}

extern "C" void kernel_launch(void* const* d_in, const int* in_sizes, int n_in,
                              void* d_out, int out_size, void* d_ws, size_t ws_size,
                              hipStream_t stream) {
    dien_fused<<<dim3(256), dim3(512), 0, stream>>>(
        (const int*)d_in[0],      // u_idx
        (const int*)d_in[1],      // i_idx
        (const int*)d_in[2],      // seq
        (const float*)d_in[3],    // item_emb
        (const float*)d_in[4],    // user_bias
        (const float*)d_in[5],    // item_bias
        (const float*)d_in[6],    // gru_w_ih
        (const float*)d_in[7],    // gru_b_ih
        (const float*)d_in[8],    // gru_w_hh
        (const float*)d_in[9],    // gru_b_hh
        (const float*)d_in[10],   // attn_w
        (const float*)d_in[11],   // attn_b
        (const float*)d_in[12],   // wr_w
        (const float*)d_in[13],   // wr_b
        (const float*)d_in[14],   // wz_w
        (const float*)d_in[15],   // wz_b
        (const float*)d_in[16],   // wh_w
        (const float*)d_in[17],   // wh_b
        (const float*)d_in[18],   // aux_w
        (const float*)d_in[19],   // aux_b
        (float*)d_out);
}